// Round 11
// baseline (91.331 us; speedup 1.0000x reference)
//
#include <hip/hip_runtime.h>
#include <math.h>

#define H 1024
#define MAXLEN 128
#define VOCAB 50257

#define ROWS_PB 16                                  // projection: rows per block (4 per wave)
#define NB_OUT ((VOCAB + ROWS_PB - 1) / ROWS_PB)    // 3142 blocks
#define NB_SUB ((VOCAB + 1023) / 1024)              // 50 blocks
#define NB_GH 768                                   // gh: 3072 rows, 1 per wave
#define NB_PRE (NB_GH + 8)                          // + 8 attn blocks (redundant logits)

__device__ inline float wave_reduce_sum(float v) {
    #pragma unroll
    for (int off = 32; off > 0; off >>= 1) v += __shfl_down(v, off);
    return v;  // lane 0 holds the sum
}

__device__ inline float dot4(float4 a, float4 b) {
    return a.x * b.x + a.y * b.y + a.z * b.z + a.w * b.w;
}

// ===== K1: gh = w_hh.h + b_hh (768 blocks)  ∥  attn logits+softmax+apply (8 blocks) =====
// gh depends only on inputs. Each attn block redundantly computes ALL 128 logits
// (1 MB W_attn, L2-shared across the 8 blocks), the softmax, and 128 columns of
// attn_applied. Redundancy multiplier is 8 — cheap (R9/R10 lesson: 256x is not).
__global__ void k_pre(const int* x, const float* h, const float* emb,
                      const float* W_attn, const float* b_attn,
                      const float* w_hh, const float* b_hh, const float* enc,
                      float* gh, float* attn_applied, float* out_attn) {
    const int t = threadIdx.x, lane = t & 63, wid = t >> 6;
    const float4* h4 = (const float4*)h;
    if (blockIdx.x < NB_GH) {
        int row = blockIdx.x * 4 + wid;              // 0..3071
        const float4* w4 = (const float4*)(w_hh + (long long)row * H);
        float acc = 0.f;
        #pragma unroll
        for (int i = 0; i < 4; i++) {
            int idx = lane + i * 64;
            acc += dot4(w4[idx], h4[idx]);
        }
        acc = wave_reduce_sum(acc);
        if (lane == 0) gh[row] = acc + b_hh[row];
    } else {
        __shared__ float lg[MAXLEN];
        __shared__ float wsm[MAXLEN];
        const float4* e4 = (const float4*)(emb + (long long)x[0] * H);
        // wave wid computes logit rows wid*32 .. wid*32+31 (same math as R8 k_attn_logits)
        #pragma unroll 2
        for (int r = 0; r < 32; r++) {
            int row = wid * 32 + r;
            const float4* w4 = (const float4*)(W_attn + row * (2 * H));
            float acc = 0.f;
            #pragma unroll
            for (int i = 0; i < 8; i++) {
                int idx = lane + i * 64;             // 512 float4 = 2048 floats
                float4 wv = w4[idx];
                float4 cv = (idx < 256) ? e4[idx] : h4[idx - 256];
                acc += dot4(wv, cv);
            }
            acc = wave_reduce_sum(acc);
            if (lane == 0) lg[row] = acc + b_attn[row];
        }
        __syncthreads();
        float m = -INFINITY;
        #pragma unroll 8
        for (int k = 0; k < MAXLEN; k++) m = fmaxf(m, lg[k]);
        if (t < MAXLEN) wsm[t] = expf(lg[t] - m);
        __syncthreads();
        float s = 0.f;
        #pragma unroll 8
        for (int k = 0; k < MAXLEN; k++) s += wsm[k];
        const float inv = 1.f / s;
        const int b = blockIdx.x - NB_GH;            // 0..7
        if (t < MAXLEN) {                            // 128 active threads
            int j = b * MAXLEN + t;
            float acc = 0.f;
            #pragma unroll 8
            for (int k = 0; k < MAXLEN; k++) acc += wsm[k] * enc[k * H + j];
            attn_applied[j] = acc * inv;
            if (b == 0) out_attn[t] = wsm[t] * inv;
        }
    }
}

// ===== K2: g[row] = relu(dot(concat(e, attn_applied), W_comb[row]) + b) — R8 verbatim =====
__global__ void k_combine(const int* x, const float* emb, const float* attn_applied,
                          const float* W_comb, const float* b_comb, float* g) {
    int wid = threadIdx.x >> 6, lane = threadIdx.x & 63;
    int row = blockIdx.x * 4 + wid;
    const float4* w4 = (const float4*)(W_comb + (long long)row * (2 * H));
    const float4* e4 = (const float4*)(emb + (long long)x[0] * H);
    const float4* a4 = (const float4*)attn_applied;
    float acc = 0.f;
    #pragma unroll
    for (int i = 0; i < 8; i++) {
        int idx = lane + i * 64;
        float4 wv = w4[idx];
        float4 cv = (idx < 256) ? e4[idx] : a4[idx - 256];
        acc += dot4(wv, cv);
    }
    acc = wave_reduce_sum(acc);
    if (lane == 0) g[row] = fmaxf(acc + b_comb[row], 0.f);
}

// ===== K3: gi (3 w_ih dots vs g) + gates -> h_new[j]; block per j — R10 verbatim =====
__global__ void k_gru(const float* g, const float* h, const float* gh,
                      const float* w_ih, const float* b_ih, float* h_new) {
    const int j = blockIdx.x, t = threadIdx.x;
    const int lane = t & 63, wid = t >> 6;
    __shared__ float red3[4][3];
    const float4* g4 = (const float4*)g;
    float4 vg = g4[t];
    float a3[3];
    #pragma unroll
    for (int gt = 0; gt < 3; gt++) {
        const float4* wi = (const float4*)(w_ih + (long long)(j + gt * H) * H);
        a3[gt] = dot4(wi[t], vg);
    }
    #pragma unroll
    for (int k = 0; k < 3; k++) {
        float v = a3[k];
        #pragma unroll
        for (int off = 32; off > 0; off >>= 1) v += __shfl_down(v, off);
        if (lane == 0) red3[wid][k] = v;
    }
    __syncthreads();
    if (t == 0) {
        float d[3];
        #pragma unroll
        for (int k = 0; k < 3; k++)
            d[k] = red3[0][k] + red3[1][k] + red3[2][k] + red3[3][k];
        float gi_r = d[0] + b_ih[j];
        float gi_z = d[1] + b_ih[j + H];
        float gi_n = d[2] + b_ih[j + 2 * H];
        float gh_r = gh[j];
        float gh_z = gh[j + H];
        float gh_n = gh[j + 2 * H];
        float r = 1.f / (1.f + expf(-(gi_r + gh_r)));
        float z = 1.f / (1.f + expf(-(gi_z + gh_z)));
        float n = tanhf(gi_n + r * gh_n);
        h_new[j] = (1.f - z) * n + z * h[j];
    }
}

// ===== K4: projection; 4 rows/wave, 16 rows/block — R8 verbatim =====
__global__ void k_out_matvec(const float* hn, const float* W_out, const float* b_out,
                             float* out, float* pmax, float* psum) {
    const int t = threadIdx.x;
    const int lane = t & 63, wid = t >> 6;
    const int row0 = blockIdx.x * ROWS_PB + wid * 4;
    __shared__ float lm[ROWS_PB];

    const float4* h4 = (const float4*)hn;
    float4 hreg[4];
    #pragma unroll
    for (int i = 0; i < 4; i++) hreg[i] = h4[lane + i * 64];

    float lv[4] = {-INFINITY, -INFINITY, -INFINITY, -INFINITY};
    if (row0 + 3 < VOCAB) {
        float4 a[4][4];
        #pragma unroll
        for (int r = 0; r < 4; r++) {
            const float4* w4 = (const float4*)(W_out + (long long)(row0 + r) * H);
            #pragma unroll
            for (int i = 0; i < 4; i++) a[r][i] = w4[lane + i * 64];
        }
        #pragma unroll
        for (int r = 0; r < 4; r++) {
            float acc = 0.f;
            #pragma unroll
            for (int i = 0; i < 4; i++) acc += dot4(a[r][i], hreg[i]);
            acc = wave_reduce_sum(acc);
            if (lane == 0) {
                lv[r] = acc + b_out[row0 + r];
                out[row0 + r] = lv[r];
            }
        }
    } else {
        for (int r = 0; r < 4; r++) {
            int row = row0 + r;
            if (row >= VOCAB) break;
            const float4* w4 = (const float4*)(W_out + (long long)row * H);
            float acc = 0.f;
            #pragma unroll
            for (int i = 0; i < 4; i++) acc += dot4(w4[lane + i * 64], hreg[i]);
            acc = wave_reduce_sum(acc);
            if (lane == 0) {
                lv[r] = acc + b_out[row];
                out[row] = lv[r];
            }
        }
    }
    if (lane == 0) {
        #pragma unroll
        for (int r = 0; r < 4; r++) lm[wid * 4 + r] = lv[r];
    }
    __syncthreads();
    if (t == 0) {
        float m = -INFINITY;
        #pragma unroll
        for (int i = 0; i < ROWS_PB; i++) m = fmaxf(m, lm[i]);
        float s = 0.f;
        #pragma unroll
        for (int i = 0; i < ROWS_PB; i++)
            if (lm[i] != -INFINITY) s += expf(lm[i] - m);
        pmax[blockIdx.x] = m;
        psum[blockIdx.x] = s;
    }
}

// ===== K5: every block redundantly merges partials, then subtracts its slice — R8 verbatim =====
__global__ void k_merge_sub(const float* pmax, const float* psum, float* out) {
    __shared__ float red[16];
    __shared__ float Msh;
    const int t = threadIdx.x;                       // 1024 threads
    const int lane = t & 63, wid = t >> 6;
    float m = -INFINITY;
    for (int i = t; i < NB_OUT; i += 1024) m = fmaxf(m, pmax[i]);
    #pragma unroll
    for (int off = 32; off > 0; off >>= 1) m = fmaxf(m, __shfl_down(m, off));
    if (lane == 0) red[wid] = m;
    __syncthreads();
    if (t == 0) {
        float mm = red[0];
        #pragma unroll
        for (int i = 1; i < 16; i++) mm = fmaxf(mm, red[i]);
        Msh = mm;
    }
    __syncthreads();
    const float M = Msh;
    float s = 0.f;
    for (int i = t; i < NB_OUT; i += 1024) s += psum[i] * expf(pmax[i] - M);
    s = wave_reduce_sum(s);
    __syncthreads();
    if (lane == 0) red[wid] = s;
    __syncthreads();
    if (t == 0) {
        float ss = 0.f;
        #pragma unroll
        for (int i = 0; i < 16; i++) ss += red[i];
        Msh = M + logf(ss);
    }
    __syncthreads();
    const float c = Msh;
    int v = blockIdx.x * 1024 + t;
    if (v < VOCAB) out[v] -= c;
}

extern "C" void kernel_launch(void* const* d_in, const int* in_sizes, int n_in,
                              void* d_out, int out_size, void* d_ws, size_t ws_size,
                              hipStream_t stream) {
    const int*   x     = (const int*)d_in[0];
    const float* h     = (const float*)d_in[1];   // [1,1,H]
    const float* enc   = (const float*)d_in[2];   // [128,H]
    const float* emb   = (const float*)d_in[3];   // [VOCAB,H]
    const float* W_attn= (const float*)d_in[4];   // [128,2H]
    const float* b_attn= (const float*)d_in[5];
    const float* W_comb= (const float*)d_in[6];   // [H,2H]
    const float* b_comb= (const float*)d_in[7];
    const float* w_ih  = (const float*)d_in[8];   // [3H,H]
    const float* w_hh  = (const float*)d_in[9];
    const float* b_ih  = (const float*)d_in[10];
    const float* b_hh  = (const float*)d_in[11];
    const float* W_out = (const float*)d_in[12];  // [VOCAB,H]
    const float* b_out = (const float*)d_in[13];

    float* out      = (float*)d_out;              // [VOCAB] log-probs
    float* out_h    = out + VOCAB;                // [H] h_new
    float* out_attn = out + VOCAB + H;            // [128] attn_w

    float* ws          = (float*)d_ws;
    float* attn_applied= ws;            // 1024
    float* g_vec       = ws + 1024;     // 1024
    float* gh          = ws + 2048;     // 3072
    float* pmax        = ws + 8192;     // NB_OUT (3142)
    float* psum        = ws + 16384;    // NB_OUT

    k_pre<<<NB_PRE, 256, 0, stream>>>(x, h, emb, W_attn, b_attn, w_hh, b_hh, enc,
                                      gh, attn_applied, out_attn);
    k_combine<<<H / 4, 256, 0, stream>>>(x, emb, attn_applied, W_comb, b_comb, g_vec);
    k_gru<<<H, 256, 0, stream>>>(g_vec, h, gh, w_ih, b_ih, out_h);
    k_out_matvec<<<NB_OUT, 256, 0, stream>>>(out_h, W_out, b_out, out, pmax, psum);
    k_merge_sub<<<NB_SUB, 1024, 0, stream>>>(pmax, psum, out);
}

// Round 12
// 82.124 us; speedup vs baseline: 1.1121x; 1.1121x over previous
//
#include <hip/hip_runtime.h>
#include <math.h>

#define H 1024
#define MAXLEN 128
#define VOCAB 50257

#define ROWS_PB 16                                  // projection: rows per block (4 per wave)
#define NB_OUT ((VOCAB + ROWS_PB - 1) / ROWS_PB)    // 3142 blocks
#define NB_SUB ((VOCAB + 1023) / 1024)              // 50 blocks
#define NB_GH2 192                                  // gh: 3072 rows, 1/wave, 16 waves/block
#define NB_PRE (NB_GH2 + 8)                         // + 8 attn blocks (fused logits+softmax+apply)

__device__ inline float wave_reduce_sum(float v) {
    #pragma unroll
    for (int off = 32; off > 0; off >>= 1) v += __shfl_down(v, off);
    return v;  // lane 0 holds the sum
}

__device__ inline float dot4(float4 a, float4 b) {
    return a.x * b.x + a.y * b.y + a.z * b.z + a.w * b.w;
}

// ===== K1 (1024 threads/block): gh (192 blocks) ∥ fused attn (8 blocks) =====
// gh: one row per wave. attn blocks: all 128 logits at 8 rows/wave via 4
// pair-ILP iterations (2 independent dot chains each — short serial depth),
// then softmax + 128 attn_applied columns per block (R8 sm_apply pattern).
__global__ void __launch_bounds__(1024, 1) k_pre(
    const int* x, const float* h, const float* emb,
    const float* W_attn, const float* b_attn,
    const float* w_hh, const float* b_hh, const float* enc,
    float* gh, float* attn_applied, float* out_attn) {
    const int t = threadIdx.x, lane = t & 63, wid = t >> 6;
    const float4* h4 = (const float4*)h;
    if (blockIdx.x < NB_GH2) {
        int row = blockIdx.x * 16 + wid;             // 0..3071
        const float4* w4 = (const float4*)(w_hh + (long long)row * H);
        float acc = 0.f;
        #pragma unroll
        for (int i = 0; i < 4; i++) {
            int idx = lane + i * 64;
            acc += dot4(w4[idx], h4[idx]);
        }
        acc = wave_reduce_sum(acc);
        if (lane == 0) gh[row] = acc + b_hh[row];
    } else {
        __shared__ float lg[MAXLEN];
        __shared__ float wsm[MAXLEN];
        const float4* e4 = (const float4*)(emb + (long long)x[0] * H);
        // wave wid: rows wid*8 .. wid*8+7, processed as 4 pairs (ILP=2)
        #pragma unroll
        for (int rp = 0; rp < 4; rp++) {
            const int row0 = wid * 8 + rp * 2;
            const float4* wA = (const float4*)(W_attn + (long long)row0 * (2 * H));
            const float4* wB = (const float4*)(W_attn + (long long)(row0 + 1) * (2 * H));
            float accA = 0.f, accB = 0.f;
            #pragma unroll
            for (int i = 0; i < 8; i++) {
                int idx = lane + i * 64;             // 512 float4 = 2048 floats
                float4 cv = (idx < 256) ? e4[idx] : h4[idx - 256];
                accA += dot4(wA[idx], cv);
                accB += dot4(wB[idx], cv);
            }
            accA = wave_reduce_sum(accA);
            accB = wave_reduce_sum(accB);
            if (lane == 0) {
                lg[row0]     = accA + b_attn[row0];
                lg[row0 + 1] = accB + b_attn[row0 + 1];
            }
        }
        __syncthreads();
        float m = -INFINITY;
        #pragma unroll 8
        for (int k = 0; k < MAXLEN; k++) m = fmaxf(m, lg[k]);
        if (t < MAXLEN) wsm[t] = expf(lg[t] - m);
        __syncthreads();
        float s = 0.f;
        #pragma unroll 8
        for (int k = 0; k < MAXLEN; k++) s += wsm[k];
        const float inv = 1.f / s;
        const int b = blockIdx.x - NB_GH2;           // 0..7
        if (t < MAXLEN) {                            // coalesced enc reads across t
            int j = b * MAXLEN + t;
            float acc = 0.f;
            #pragma unroll 8
            for (int k = 0; k < MAXLEN; k++) acc += wsm[k] * enc[k * H + j];
            attn_applied[j] = acc * inv;
            if (b == 0) out_attn[t] = wsm[t] * inv;
        }
    }
}

// ===== K2: g[row] = relu(dot(concat(e, attn_applied), W_comb[row]) + b) — R8 verbatim =====
__global__ void k_combine(const int* x, const float* emb, const float* attn_applied,
                          const float* W_comb, const float* b_comb, float* g) {
    int wid = threadIdx.x >> 6, lane = threadIdx.x & 63;
    int row = blockIdx.x * 4 + wid;
    const float4* w4 = (const float4*)(W_comb + (long long)row * (2 * H));
    const float4* e4 = (const float4*)(emb + (long long)x[0] * H);
    const float4* a4 = (const float4*)attn_applied;
    float acc = 0.f;
    #pragma unroll
    for (int i = 0; i < 8; i++) {
        int idx = lane + i * 64;
        float4 wv = w4[idx];
        float4 cv = (idx < 256) ? e4[idx] : a4[idx - 256];
        acc += dot4(wv, cv);
    }
    acc = wave_reduce_sum(acc);
    if (lane == 0) g[row] = fmaxf(acc + b_comb[row], 0.f);
}

// ===== K3: gi (3 w_ih dots vs g) + gates -> h_new[j]; block per j — R10 verbatim =====
__global__ void k_gru(const float* g, const float* h, const float* gh,
                      const float* w_ih, const float* b_ih, float* h_new) {
    const int j = blockIdx.x, t = threadIdx.x;
    const int lane = t & 63, wid = t >> 6;
    __shared__ float red3[4][3];
    const float4* g4 = (const float4*)g;
    float4 vg = g4[t];
    float a3[3];
    #pragma unroll
    for (int gt = 0; gt < 3; gt++) {
        const float4* wi = (const float4*)(w_ih + (long long)(j + gt * H) * H);
        a3[gt] = dot4(wi[t], vg);
    }
    #pragma unroll
    for (int k = 0; k < 3; k++) {
        float v = a3[k];
        #pragma unroll
        for (int off = 32; off > 0; off >>= 1) v += __shfl_down(v, off);
        if (lane == 0) red3[wid][k] = v;
    }
    __syncthreads();
    if (t == 0) {
        float d[3];
        #pragma unroll
        for (int k = 0; k < 3; k++)
            d[k] = red3[0][k] + red3[1][k] + red3[2][k] + red3[3][k];
        float gi_r = d[0] + b_ih[j];
        float gi_z = d[1] + b_ih[j + H];
        float gi_n = d[2] + b_ih[j + 2 * H];
        float gh_r = gh[j];
        float gh_z = gh[j + H];
        float gh_n = gh[j + 2 * H];
        float r = 1.f / (1.f + expf(-(gi_r + gh_r)));
        float z = 1.f / (1.f + expf(-(gi_z + gh_z)));
        float n = tanhf(gi_n + r * gh_n);
        h_new[j] = (1.f - z) * n + z * h[j];
    }
}

// ===== K4: projection; 4 rows/wave, 16 rows/block — R8 verbatim =====
__global__ void k_out_matvec(const float* hn, const float* W_out, const float* b_out,
                             float* out, float* pmax, float* psum) {
    const int t = threadIdx.x;
    const int lane = t & 63, wid = t >> 6;
    const int row0 = blockIdx.x * ROWS_PB + wid * 4;
    __shared__ float lm[ROWS_PB];

    const float4* h4 = (const float4*)hn;
    float4 hreg[4];
    #pragma unroll
    for (int i = 0; i < 4; i++) hreg[i] = h4[lane + i * 64];

    float lv[4] = {-INFINITY, -INFINITY, -INFINITY, -INFINITY};
    if (row0 + 3 < VOCAB) {
        float4 a[4][4];
        #pragma unroll
        for (int r = 0; r < 4; r++) {
            const float4* w4 = (const float4*)(W_out + (long long)(row0 + r) * H);
            #pragma unroll
            for (int i = 0; i < 4; i++) a[r][i] = w4[lane + i * 64];
        }
        #pragma unroll
        for (int r = 0; r < 4; r++) {
            float acc = 0.f;
            #pragma unroll
            for (int i = 0; i < 4; i++) acc += dot4(a[r][i], hreg[i]);
            acc = wave_reduce_sum(acc);
            if (lane == 0) {
                lv[r] = acc + b_out[row0 + r];
                out[row0 + r] = lv[r];
            }
        }
    } else {
        for (int r = 0; r < 4; r++) {
            int row = row0 + r;
            if (row >= VOCAB) break;
            const float4* w4 = (const float4*)(W_out + (long long)row * H);
            float acc = 0.f;
            #pragma unroll
            for (int i = 0; i < 4; i++) acc += dot4(w4[lane + i * 64], hreg[i]);
            acc = wave_reduce_sum(acc);
            if (lane == 0) {
                lv[r] = acc + b_out[row];
                out[row] = lv[r];
            }
        }
    }
    if (lane == 0) {
        #pragma unroll
        for (int r = 0; r < 4; r++) lm[wid * 4 + r] = lv[r];
    }
    __syncthreads();
    if (t == 0) {
        float m = -INFINITY;
        #pragma unroll
        for (int i = 0; i < ROWS_PB; i++) m = fmaxf(m, lm[i]);
        float s = 0.f;
        #pragma unroll
        for (int i = 0; i < ROWS_PB; i++)
            if (lm[i] != -INFINITY) s += expf(lm[i] - m);
        pmax[blockIdx.x] = m;
        psum[blockIdx.x] = s;
    }
}

// ===== K5: every block redundantly merges partials, then subtracts its slice — R8 verbatim =====
__global__ void k_merge_sub(const float* pmax, const float* psum, float* out) {
    __shared__ float red[16];
    __shared__ float Msh;
    const int t = threadIdx.x;                       // 1024 threads
    const int lane = t & 63, wid = t >> 6;
    float m = -INFINITY;
    for (int i = t; i < NB_OUT; i += 1024) m = fmaxf(m, pmax[i]);
    #pragma unroll
    for (int off = 32; off > 0; off >>= 1) m = fmaxf(m, __shfl_down(m, off));
    if (lane == 0) red[wid] = m;
    __syncthreads();
    if (t == 0) {
        float mm = red[0];
        #pragma unroll
        for (int i = 1; i < 16; i++) mm = fmaxf(mm, red[i]);
        Msh = mm;
    }
    __syncthreads();
    const float M = Msh;
    float s = 0.f;
    for (int i = t; i < NB_OUT; i += 1024) s += psum[i] * expf(pmax[i] - M);
    s = wave_reduce_sum(s);
    __syncthreads();
    if (lane == 0) red[wid] = s;
    __syncthreads();
    if (t == 0) {
        float ss = 0.f;
        #pragma unroll
        for (int i = 0; i < 16; i++) ss += red[i];
        Msh = M + logf(ss);
    }
    __syncthreads();
    const float c = Msh;
    int v = blockIdx.x * 1024 + t;
    if (v < VOCAB) out[v] -= c;
}

extern "C" void kernel_launch(void* const* d_in, const int* in_sizes, int n_in,
                              void* d_out, int out_size, void* d_ws, size_t ws_size,
                              hipStream_t stream) {
    const int*   x     = (const int*)d_in[0];
    const float* h     = (const float*)d_in[1];   // [1,1,H]
    const float* enc   = (const float*)d_in[2];   // [128,H]
    const float* emb   = (const float*)d_in[3];   // [VOCAB,H]
    const float* W_attn= (const float*)d_in[4];   // [128,2H]
    const float* b_attn= (const float*)d_in[5];
    const float* W_comb= (const float*)d_in[6];   // [H,2H]
    const float* b_comb= (const float*)d_in[7];
    const float* w_ih  = (const float*)d_in[8];   // [3H,H]
    const float* w_hh  = (const float*)d_in[9];
    const float* b_ih  = (const float*)d_in[10];
    const float* b_hh  = (const float*)d_in[11];
    const float* W_out = (const float*)d_in[12];  // [VOCAB,H]
    const float* b_out = (const float*)d_in[13];

    float* out      = (float*)d_out;              // [VOCAB] log-probs
    float* out_h    = out + VOCAB;                // [H] h_new
    float* out_attn = out + VOCAB + H;            // [128] attn_w

    float* ws          = (float*)d_ws;
    float* attn_applied= ws;            // 1024
    float* g_vec       = ws + 1024;     // 1024
    float* gh          = ws + 2048;     // 3072
    float* pmax        = ws + 8192;     // NB_OUT (3142)
    float* psum        = ws + 16384;    // NB_OUT

    k_pre<<<NB_PRE, 1024, 0, stream>>>(x, h, emb, W_attn, b_attn, w_hh, b_hh, enc,
                                       gh, attn_applied, out_attn);
    k_combine<<<H / 4, 256, 0, stream>>>(x, emb, attn_applied, W_comb, b_comb, g_vec);
    k_gru<<<H, 256, 0, stream>>>(g_vec, h, gh, w_ih, b_ih, out_h);
    k_out_matvec<<<NB_OUT, 256, 0, stream>>>(out_h, W_out, b_out, out, pmax, psum);
    k_merge_sub<<<NB_SUB, 1024, 0, stream>>>(pmax, psum, out);
}

// Round 13
// 67.480 us; speedup vs baseline: 1.3534x; 1.2170x over previous
//
#include <hip/hip_runtime.h>
#include <math.h>

#define H 1024
#define MAXLEN 128
#define VOCAB 50257

#define ROWS_PB 16                                  // projection: rows per block (4 per wave)
#define NB_OUT ((VOCAB + ROWS_PB - 1) / ROWS_PB)    // 3142 blocks
#define NB_SUB ((VOCAB + 1023) / 1024)              // 50 blocks
#define NB_GH 768                                   // gh: 3072 rows, 1 per wave, 256-thread blocks
#define NB_PRE (NB_GH + 32)                         // + 32 blocks for 128 attn-logit rows

__device__ inline float wave_reduce_sum(float v) {
    #pragma unroll
    for (int off = 32; off > 0; off >>= 1) v += __shfl_down(v, off);
    return v;  // lane 0 holds the sum
}

__device__ inline float dot4(float4 a, float4 b) {
    return a.x * b.x + a.y * b.y + a.z * b.z + a.w * b.w;
}

// ===== K1: gh = w_hh.h + b_hh (768 blocks) ∥ attn logits (32 blocks) — R10 verbatim =====
__global__ void k_pre(const int* x, const float* h, const float* emb,
                      const float* W_attn, const float* b_attn,
                      const float* w_hh, const float* b_hh,
                      float* gh, float* logits) {
    const int lane = threadIdx.x & 63, wid = threadIdx.x >> 6;
    const float4* h4 = (const float4*)h;
    if (blockIdx.x < NB_GH) {
        int row = blockIdx.x * 4 + wid;              // 0..3071
        const float4* w4 = (const float4*)(w_hh + (long long)row * H);
        float acc = 0.f;
        #pragma unroll
        for (int i = 0; i < 4; i++) {
            int idx = lane + i * 64;
            acc += dot4(w4[idx], h4[idx]);
        }
        acc = wave_reduce_sum(acc);
        if (lane == 0) gh[row] = acc + b_hh[row];
    } else {
        int row = (blockIdx.x - NB_GH) * 4 + wid;    // 0..127
        const float4* w4 = (const float4*)(W_attn + row * (2 * H));
        const float4* e4 = (const float4*)(emb + (long long)x[0] * H);
        float acc = 0.f;
        #pragma unroll
        for (int i = 0; i < 8; i++) {
            int idx = lane + i * 64;                 // 512 float4 = 2048 floats
            float4 wv = w4[idx];
            float4 cv = (idx < 256) ? e4[idx] : h4[idx - 256];
            acc += dot4(wv, cv);
        }
        acc = wave_reduce_sum(acc);
        if (lane == 0) logits[row] = acc + b_attn[row];
    }
}

// ===== K2: redundant softmax(128) per block + attn apply — R8 verbatim =====
__global__ void k_attn_sm_apply(const float* logits, const float* enc,
                                float* attn_applied, float* out_attn) {
    __shared__ float buf[MAXLEN];
    __shared__ float wsm[MAXLEN];
    int t = threadIdx.x;
    if (t < MAXLEN) buf[t] = logits[t];
    __syncthreads();
    float m = -INFINITY;
    #pragma unroll 8
    for (int k = 0; k < MAXLEN; k++) m = fmaxf(m, buf[k]);
    if (t < MAXLEN) wsm[t] = expf(buf[t] - m);
    __syncthreads();
    float s = 0.f;
    #pragma unroll 8
    for (int k = 0; k < MAXLEN; k++) s += wsm[k];
    float inv = 1.f / s;
    if (t < MAXLEN) {                        // 128 active threads per block
        int j = blockIdx.x * MAXLEN + t;
        float acc = 0.f;
        #pragma unroll 8
        for (int k = 0; k < MAXLEN; k++) acc += wsm[k] * enc[k * H + j];
        attn_applied[j] = acc * inv;
        if (blockIdx.x == 0) out_attn[t] = wsm[t] * inv;
    }
}

// ===== K3: g[row] = relu(dot(concat(e, attn_applied), W_comb[row]) + b) — R8 verbatim =====
__global__ void k_combine(const int* x, const float* emb, const float* attn_applied,
                          const float* W_comb, const float* b_comb, float* g) {
    int wid = threadIdx.x >> 6, lane = threadIdx.x & 63;
    int row = blockIdx.x * 4 + wid;
    const float4* w4 = (const float4*)(W_comb + (long long)row * (2 * H));
    const float4* e4 = (const float4*)(emb + (long long)x[0] * H);
    const float4* a4 = (const float4*)attn_applied;
    float acc = 0.f;
    #pragma unroll
    for (int i = 0; i < 8; i++) {
        int idx = lane + i * 64;
        float4 wv = w4[idx];
        float4 cv = (idx < 256) ? e4[idx] : a4[idx - 256];
        acc += dot4(wv, cv);
    }
    acc = wave_reduce_sum(acc);
    if (lane == 0) g[row] = fmaxf(acc + b_comb[row], 0.f);
}

// ===== K4: gi (3 w_ih dots vs g) + gates -> h_new[j]; block per j — R10 verbatim =====
__global__ void k_gru(const float* g, const float* h, const float* gh,
                      const float* w_ih, const float* b_ih, float* h_new) {
    const int j = blockIdx.x, t = threadIdx.x;
    const int lane = t & 63, wid = t >> 6;
    __shared__ float red3[4][3];
    const float4* g4 = (const float4*)g;
    float4 vg = g4[t];
    float a3[3];
    #pragma unroll
    for (int gt = 0; gt < 3; gt++) {
        const float4* wi = (const float4*)(w_ih + (long long)(j + gt * H) * H);
        a3[gt] = dot4(wi[t], vg);
    }
    #pragma unroll
    for (int k = 0; k < 3; k++) {
        float v = a3[k];
        #pragma unroll
        for (int off = 32; off > 0; off >>= 1) v += __shfl_down(v, off);
        if (lane == 0) red3[wid][k] = v;
    }
    __syncthreads();
    if (t == 0) {
        float d[3];
        #pragma unroll
        for (int k = 0; k < 3; k++)
            d[k] = red3[0][k] + red3[1][k] + red3[2][k] + red3[3][k];
        float gi_r = d[0] + b_ih[j];
        float gi_z = d[1] + b_ih[j + H];
        float gi_n = d[2] + b_ih[j + 2 * H];
        float gh_r = gh[j];
        float gh_z = gh[j + H];
        float gh_n = gh[j + 2 * H];
        float r = 1.f / (1.f + expf(-(gi_r + gh_r)));
        float z = 1.f / (1.f + expf(-(gi_z + gh_z)));
        float n = tanhf(gi_n + r * gh_n);
        h_new[j] = (1.f - z) * n + z * h[j];
    }
}

// ===== K5: projection; 4 rows/wave, 16 rows/block — R8 verbatim =====
__global__ void k_out_matvec(const float* hn, const float* W_out, const float* b_out,
                             float* out, float* pmax, float* psum) {
    const int t = threadIdx.x;
    const int lane = t & 63, wid = t >> 6;
    const int row0 = blockIdx.x * ROWS_PB + wid * 4;
    __shared__ float lm[ROWS_PB];

    const float4* h4 = (const float4*)hn;
    float4 hreg[4];
    #pragma unroll
    for (int i = 0; i < 4; i++) hreg[i] = h4[lane + i * 64];

    float lv[4] = {-INFINITY, -INFINITY, -INFINITY, -INFINITY};
    if (row0 + 3 < VOCAB) {
        float4 a[4][4];
        #pragma unroll
        for (int r = 0; r < 4; r++) {
            const float4* w4 = (const float4*)(W_out + (long long)(row0 + r) * H);
            #pragma unroll
            for (int i = 0; i < 4; i++) a[r][i] = w4[lane + i * 64];
        }
        #pragma unroll
        for (int r = 0; r < 4; r++) {
            float acc = 0.f;
            #pragma unroll
            for (int i = 0; i < 4; i++) acc += dot4(a[r][i], hreg[i]);
            acc = wave_reduce_sum(acc);
            if (lane == 0) {
                lv[r] = acc + b_out[row0 + r];
                out[row0 + r] = lv[r];
            }
        }
    } else {
        for (int r = 0; r < 4; r++) {
            int row = row0 + r;
            if (row >= VOCAB) break;
            const float4* w4 = (const float4*)(W_out + (long long)row * H);
            float acc = 0.f;
            #pragma unroll
            for (int i = 0; i < 4; i++) acc += dot4(w4[lane + i * 64], hreg[i]);
            acc = wave_reduce_sum(acc);
            if (lane == 0) {
                lv[r] = acc + b_out[row];
                out[row] = lv[r];
            }
        }
    }
    if (lane == 0) {
        #pragma unroll
        for (int r = 0; r < 4; r++) lm[wid * 4 + r] = lv[r];
    }
    __syncthreads();
    if (t == 0) {
        float m = -INFINITY;
        #pragma unroll
        for (int i = 0; i < ROWS_PB; i++) m = fmaxf(m, lm[i]);
        float s = 0.f;
        #pragma unroll
        for (int i = 0; i < ROWS_PB; i++)
            if (lm[i] != -INFINITY) s += expf(lm[i] - m);
        pmax[blockIdx.x] = m;
        psum[blockIdx.x] = s;
    }
}

// ===== K6: every block redundantly merges partials, then subtracts its slice — R8 verbatim =====
__global__ void k_merge_sub(const float* pmax, const float* psum, float* out) {
    __shared__ float red[16];
    __shared__ float Msh;
    const int t = threadIdx.x;                       // 1024 threads
    const int lane = t & 63, wid = t >> 6;
    float m = -INFINITY;
    for (int i = t; i < NB_OUT; i += 1024) m = fmaxf(m, pmax[i]);
    #pragma unroll
    for (int off = 32; off > 0; off >>= 1) m = fmaxf(m, __shfl_down(m, off));
    if (lane == 0) red[wid] = m;
    __syncthreads();
    if (t == 0) {
        float mm = red[0];
        #pragma unroll
        for (int i = 1; i < 16; i++) mm = fmaxf(mm, red[i]);
        Msh = mm;
    }
    __syncthreads();
    const float M = Msh;
    float s = 0.f;
    for (int i = t; i < NB_OUT; i += 1024) s += psum[i] * expf(pmax[i] - M);
    s = wave_reduce_sum(s);
    __syncthreads();
    if (lane == 0) red[wid] = s;
    __syncthreads();
    if (t == 0) {
        float ss = 0.f;
        #pragma unroll
        for (int i = 0; i < 16; i++) ss += red[i];
        Msh = M + logf(ss);
    }
    __syncthreads();
    const float c = Msh;
    int v = blockIdx.x * 1024 + t;
    if (v < VOCAB) out[v] -= c;
}

extern "C" void kernel_launch(void* const* d_in, const int* in_sizes, int n_in,
                              void* d_out, int out_size, void* d_ws, size_t ws_size,
                              hipStream_t stream) {
    const int*   x     = (const int*)d_in[0];
    const float* h     = (const float*)d_in[1];   // [1,1,H]
    const float* enc   = (const float*)d_in[2];   // [128,H]
    const float* emb   = (const float*)d_in[3];   // [VOCAB,H]
    const float* W_attn= (const float*)d_in[4];   // [128,2H]
    const float* b_attn= (const float*)d_in[5];
    const float* W_comb= (const float*)d_in[6];   // [H,2H]
    const float* b_comb= (const float*)d_in[7];
    const float* w_ih  = (const float*)d_in[8];   // [3H,H]
    const float* w_hh  = (const float*)d_in[9];
    const float* b_ih  = (const float*)d_in[10];
    const float* b_hh  = (const float*)d_in[11];
    const float* W_out = (const float*)d_in[12];  // [VOCAB,H]
    const float* b_out = (const float*)d_in[13];

    float* out      = (float*)d_out;              // [VOCAB] log-probs
    float* out_h    = out + VOCAB;                // [H] h_new
    float* out_attn = out + VOCAB + H;            // [128] attn_w

    float* ws          = (float*)d_ws;
    float* logits128   = ws;            // 128
    float* attn_applied= ws + 256;      // 1024
    float* g_vec       = ws + 1280;     // 1024
    float* gh          = ws + 2560;     // 3072
    float* pmax        = ws + 8192;     // NB_OUT (3142)
    float* psum        = ws + 16384;    // NB_OUT

    k_pre<<<NB_PRE, 256, 0, stream>>>(x, h, emb, W_attn, b_attn, w_hh, b_hh,
                                      gh, logits128);
    k_attn_sm_apply<<<H / MAXLEN, 256, 0, stream>>>(logits128, enc, attn_applied, out_attn);
    k_combine<<<H / 4, 256, 0, stream>>>(x, emb, attn_applied, W_comb, b_comb, g_vec);
    k_gru<<<H, 256, 0, stream>>>(g_vec, h, gh, w_ih, b_ih, out_h);
    k_out_matvec<<<NB_OUT, 256, 0, stream>>>(out_h, W_out, b_out, out, pmax, psum);
    k_merge_sub<<<NB_SUB, 1024, 0, stream>>>(pmax, psum, out);
}